// Round 7
// baseline (223.733 us; speedup 1.0000x reference)
//
#include <hip/hip_runtime.h>

#define NGS 25
#define NGX 40
#define NGY 40
#define KK  64
#define NB2 4
#define NYY 1000
#define PTOT 625
#define PC  64
#define NCH 10
#define DAMP 0.01f

typedef __attribute__((ext_vector_type(8))) short short8;
typedef __attribute__((ext_vector_type(4))) float f32x4;

__device__ __forceinline__ short bf16_rn(float x) {
  unsigned u = __float_as_uint(x);
  u = u + 0x7fffu + ((u >> 16) & 1u);
  return (short)(u >> 16);
}
__device__ __forceinline__ float bf16_tof(short s) {
  return __uint_as_float(((unsigned)(unsigned short)s) << 16);
}

// ---------------- Kernel 1: MFMA Gram (bf16 hi/lo) + register Gauss-Jordan ---
// PC=64 chunks -> 20.5 KB planes -> ~6-7 blocks/CU resident (vs 3 at PC=128):
// stage/MFMA phases of different blocks overlap instead of phase-locking.
__global__ __launch_bounds__(256, 8) void k_gram_solve(
    const float* __restrict__ xin, const float* __restrict__ hist,
    float* __restrict__ AG)
{
  __shared__ __align__(16) short smem[2 * 80 * PC + 2 * 72 * 2];  // planes + prow
  short* Vhi = smem;
  short* Vlo = smem + 80 * PC;
  float (*Gs)[KK + 5] = (float (*)[KK + 5])smem;       // 64x69 fp32, aliases planes
  float* prow = ((float*)smem) + (2 * 80 * PC) / 2;    // past planes: 2x72 fp32

  const int tile = blockIdx.x;
  const int gx = tile / NGY, gy = tile % NGY;
  const size_t base = (size_t)(gx * NGS) * NYY + (size_t)(gy * NGS);
  const int tid  = threadIdx.x;
  const int wave = tid >> 6;
  const int lane = tid & 63;
  const int u    = lane >> 4;     // k-group 0..3
  const int col  = lane & 15;

  // staging coords: pp = tid&63 (k position), rb = tid>>6 (row group 0..3)
  const int pp = tid & 63;
  const int rb = tid >> 6;

  // zero-pad rows 68..79 once (X-fragment rows col>=4; never overwritten)
  for (int i = tid + 68 * PC; i < 80 * PC; i += 256) { Vhi[i] = 0; Vlo[i] = 0; }

  f32x4 accG[4];
  #pragma unroll
  for (int j = 0; j < 4; ++j) { accG[j].x = 0.f; accG[j].y = 0.f; accG[j].z = 0.f; accG[j].w = 0.f; }
  f32x4 accX; accX.x = 0.f; accX.y = 0.f; accX.z = 0.f; accX.w = 0.f;

  const int rA = 16 * wave + col;
  const int rX = KK + col;

  // truncation hi-split; lo captures residual to bf16 precision
  #define STW(r, val) { \
    const short h = (short)(__float_as_uint(val) >> 16); \
    const short l = bf16_rn((val) - bf16_tof(h)); \
    const int off = (r) * PC + ((((pp >> 3) ^ ((r) & 7)) << 3) | (pp & 7)); \
    Vhi[off] = h; Vlo[off] = l; }

  for (int ch = 0; ch < NCH; ++ch) {
    const int p = ch * PC + pp;
    const bool inb = (p < PTOT);
    const int px = p / NGS, py = p - px * NGS;
    const size_t a = base + (size_t)px * NYY + py;

    // ---- 2-batch prefetch: 9 + 8 loads in flight, converts interleaved
    float v0[9], v1[8];
    #pragma unroll
    for (int it = 0; it < 9; ++it)
      v0[it] = inb ? hist[(size_t)(rb + 4 * it) * 1000000 + a] : 0.f;
    #pragma unroll
    for (int it = 0; it < 8; ++it) {
      v1[it] = inb ? ((it < 7) ? hist[(size_t)(rb + 4 * (it + 9)) * 1000000 + a]
                               : xin[(size_t)rb * 1000000 + a]) : 0.f;
    }
    #pragma unroll
    for (int it = 0; it < 9; ++it) STW(rb + 4 * it, v0[it]);
    #pragma unroll
    for (int it = 0; it < 8; ++it) {
      const int r = (it < 7) ? (rb + 4 * (it + 9)) : (KK + rb);
      STW(r, v1[it]);
    }
    __syncthreads();

    // ---- 2 K-steps of 32 per chunk
    #pragma unroll
    for (int t = 0; t < 2; ++t) {
      const int k8 = t * 4 + u;
      #define FRG(P, r) (*(const short8*)&P[(r) * PC + (((k8) ^ ((r) & 7)) << 3)])
      const short8 a_hi = FRG(Vhi, rA);
      const short8 a_lo = FRG(Vlo, rA);
      const short8 x_hi = FRG(Vhi, rX);
      const short8 x_lo = FRG(Vlo, rX);
      short8 b_hi[4], b_lo[4];
      #pragma unroll
      for (int s = 0; s < 4; ++s) {
        b_hi[s] = FRG(Vhi, 16 * s + col);
        b_lo[s] = FRG(Vlo, 16 * s + col);
      }
      #undef FRG
      #pragma unroll
      for (int j = 0; j < 4; ++j) {
        accG[j] = __builtin_amdgcn_mfma_f32_16x16x32_bf16(a_hi, b_hi[j], accG[j], 0, 0, 0);
        accG[j] = __builtin_amdgcn_mfma_f32_16x16x32_bf16(a_hi, b_lo[j], accG[j], 0, 0, 0);
        accG[j] = __builtin_amdgcn_mfma_f32_16x16x32_bf16(a_lo, b_hi[j], accG[j], 0, 0, 0);
      }
      accX = __builtin_amdgcn_mfma_f32_16x16x32_bf16(x_hi, a_hi, accX, 0, 0, 0);
      accX = __builtin_amdgcn_mfma_f32_16x16x32_bf16(x_hi, a_lo, accX, 0, 0, 0);
      accX = __builtin_amdgcn_mfma_f32_16x16x32_bf16(x_lo, a_hi, accX, 0, 0, 0);
    }
    __syncthreads();
  }
  #undef STW

  // ---- write G (+damping) into Gs (aliases planes; all plane reads done)
  const int row4 = u * 4;
  #pragma unroll
  for (int j = 0; j < 4; ++j)
    #pragma unroll
    for (int q = 0; q < 4; ++q) {
      const int gr = 16 * wave + row4 + q;
      const int gc = 16 * j + col;
      float g = (q == 0) ? accG[j].x : (q == 1) ? accG[j].y : (q == 2) ? accG[j].z : accG[j].w;
      Gs[gr][gc] = g + ((gr == gc) ? DAMP : 0.f);
    }
  if (lane < 16) {
    Gs[16 * wave + lane][KK + 0] = accX.x;
    Gs[16 * wave + lane][KK + 1] = accX.y;
    Gs[16 * wave + lane][KK + 2] = accX.z;
    Gs[16 * wave + lane][KK + 3] = accX.w;
  }
  __syncthreads();

  // ---- register Gauss-Jordan: thread (ei,eq) owns cols {eq+4jj} of row ei ----
  const int ei = tid >> 2, eq = tid & 3;
  float v[17];
  #pragma unroll
  for (int jj = 0; jj < 17; ++jj) v[jj] = Gs[ei][4 * jj + eq];

  float myDiag = 1.f;
  if (ei == 0) {
    #pragma unroll
    for (int jj = 0; jj < 17; ++jj) prow[4 * jj + eq] = v[jj];
  }
  __syncthreads();

  #pragma unroll
  for (int k = 0; k < KK; ++k) {
    const float* pr = prow + (k & 1) * 72;
    const float piv = pr[k];
    const float num = __shfl(v[k >> 2], (lane & ~3) | (k & 3), 64);
    const float f = (ei == k) ? 0.f : (num / piv);
    if (ei == k) myDiag = piv;
    #pragma unroll
    for (int jj = (k < 3 ? 0 : (k - 2) >> 2); jj < 17; ++jj)
      v[jj] -= f * pr[4 * jj + eq];
    if (k < KK - 1) {
      if (ei == k + 1) {
        float* pw = prow + ((k + 1) & 1) * 72;
        #pragma unroll
        for (int jj = 0; jj < 17; ++jj) pw[4 * jj + eq] = v[jj];
      }
    }
    __syncthreads();
  }

  AG[(size_t)tile * 256 + eq * 64 + ei] = v[16] / myDiag;
}

// ---------------- Kernel 2: Y = AG * V, scatter to output ---------------------
__global__ __launch_bounds__(256) void k_project(
    const float* __restrict__ hist, const float* __restrict__ AG,
    float* __restrict__ out)
{
  __shared__ float ag[KK][NB2];   // ag[k][c]
  const int tile = blockIdx.x;
  const int gx = tile / NGY, gy = tile % NGY;
  const size_t base = (size_t)(gx * NGS) * NYY + (size_t)(gy * NGS);
  const int tid = threadIdx.x;
  {
    const int c = tid >> 6, k = tid & 63;
    ag[k][c] = AG[(size_t)tile * 256 + tid];   // AG[c][k] -> ag[k][c]
  }
  __syncthreads();

  const int p1 = tid, p2 = tid + 256, p3 = tid + 512;
  const int a1 = (p1 / NGS) * NYY + (p1 % NGS);
  const int a2 = (p2 / NGS) * NYY + (p2 % NGS);
  const bool has3 = (p3 < PTOT);
  const int a3 = has3 ? ((p3 / NGS) * NYY + (p3 % NGS)) : 0;

  float o1[4] = {0,0,0,0}, o2[4] = {0,0,0,0}, o3[4] = {0,0,0,0};
  const float4* ag4 = (const float4*)ag;

  #pragma unroll 4
  for (int k = 0; k < KK; ++k) {
    const size_t ko = (size_t)k * 1000000 + base;
    const float v1 = hist[ko + a1];
    const float v2 = hist[ko + a2];
    const float v3 = has3 ? hist[ko + a3] : 0.f;
    const float4 w = ag4[k];
    o1[0] += w.x * v1; o1[1] += w.y * v1; o1[2] += w.z * v1; o1[3] += w.w * v1;
    o2[0] += w.x * v2; o2[1] += w.y * v2; o2[2] += w.z * v2; o2[3] += w.w * v2;
    o3[0] += w.x * v3; o3[1] += w.y * v3; o3[2] += w.z * v3; o3[3] += w.w * v3;
  }

  out[(size_t)0 * 1000000 + base + a1] = o1[0];
  out[(size_t)1 * 1000000 + base + a1] = o1[1];
  out[(size_t)2 * 1000000 + base + a1] = o1[2];
  out[(size_t)3 * 1000000 + base + a1] = o1[3];
  out[(size_t)0 * 1000000 + base + a2] = o2[0];
  out[(size_t)1 * 1000000 + base + a2] = o2[1];
  out[(size_t)2 * 1000000 + base + a2] = o2[2];
  out[(size_t)3 * 1000000 + base + a2] = o2[3];
  if (has3) {
    out[(size_t)0 * 1000000 + base + a3] = o3[0];
    out[(size_t)1 * 1000000 + base + a3] = o3[1];
    out[(size_t)2 * 1000000 + base + a3] = o3[2];
    out[(size_t)3 * 1000000 + base + a3] = o3[3];
  }
}

extern "C" void kernel_launch(void* const* d_in, const int* in_sizes, int n_in,
                              void* d_out, int out_size, void* d_ws, size_t ws_size,
                              hipStream_t stream) {
  const float* xin  = (const float*)d_in[0];   // local_x  (1,4,1000,1000)
  const float* hist = (const float*)d_in[1];   // ms_history (1,16,4,1000,1000)
  float* out = (float*)d_out;
  float* AG  = (float*)d_ws;                   // 1600 * 256 floats = 1.6 MB

  k_gram_solve<<<NGX * NGY, 256, 0, stream>>>(xin, hist, AG);
  k_project  <<<NGX * NGY, 256, 0, stream>>>(hist, AG, out);
}